// Round 24
// baseline (58.720 us; speedup 1.0000x reference)
//
#include <hip/hip_runtime.h>
#include <cstdint>

// Problem constants (B=8, C=80, H=W=128, K=100, kernel=3, num_dets=1000)
#define NB    8
#define NC    80
#define HH    128
#define WW    128
#define HW    16384
#define CHW   1310720
#define KTOP  100
#define NDET  1000
#define NPAIR 10000
#define CAP   4096
#define ACAP  2048
#define NBINS 4096        // fallback hist: 12-bit bins over sigmoid bits (>>19)
#define VTHR  3.5f        // fixed conservative raw threshold; exactness VERIFIED by count
#define NTILE (24 * NC * 4)   // 7680 quarter-tiles
#define NBLK  2048            // persistent blocks: 8 per CU

// ---- workspace layout (bytes) ----
#define OFF_CCNT   0                         // int[24*32] fast-path counts (128B apart)
#define ZERO_BYTES 3072                      // ccnt only
#define OFF_CAND   3072                      // u64[24][4096]
#define OFF_CS     789504                    // float[2400]
#define OFF_CX     799104
#define OFF_CY     808704
#define OFF_CE     818304
#define OFF_CCLS   827904                    // int[2400]
#define WS_NEEDED  837504                    // ~0.84 MB

// branchless, bit-identical to jax.nn.sigmoid's two-branch form
__device__ __forceinline__ float sigmoidf(float x) {
    float e = expf(-fabsf(x));
    return (x >= 0.f ? 1.f : e) / (1.f + e);
}

// ---- kernel 1: PERSISTENT quarter-tile NMS ----
// 2048 blocks (8/CU, resident whole kernel) grid-stride over 7680 tiles.
// Per iteration: issue next tile's global loads BEFORE the LDS-protect barrier
// (latency hides under other waves' stencil of the previous tile); no block
// launch/teardown per tile. Stencil + emission identical to R23 (proven exact).
__global__ void __launch_bounds__(256) k_nms(
        const float* __restrict__ tl, const float* __restrict__ br,
        const float* __restrict__ ct,
        uint64_t* __restrict__ cand, int* __restrict__ ccnt) {
    __shared__ float lds[34 * WW];   // 17408 B

    int tid = threadIdx.x;
    const float NEG = -__builtin_inff();

    for (int tile = blockIdx.x; tile < NTILE; tile += NBLK) {
        int bc = tile / 320;                 // 80 chans * 4 quarters per bc
        int rem_b = tile - bc * 320;
        int chan = rem_b >> 2;
        int q = rem_b & 3;
        int t = bc >> 3; int b = bc & 7;
        const float* heat = (t == 0) ? tl : (t == 1) ? br : ct;
        const float* cb = heat + (size_t)b * CHW + (size_t)chan * HW;
        int ybase = q * 32;

        // stage: 34 rows x 32 float4 = 1088 elems; 4 guaranteed + 1 cond load.
        // Loads issue BEFORE the barrier (global only - no LDS hazard).
        #define GADDR(K, GY) ({ int r_ = (K) >> 5; (GY) = ybase - 1 + r_; \
                                int gyc_ = min(max((GY), 0), HH - 1); \
                                cb + gyc_ * WW + (((K) & 31) << 2); })
        int gy0, gy1, gy2, gy3, gy4 = 0;
        const float* a0 = GADDR(tid,        gy0);
        const float* a1 = GADDR(tid + 256,  gy1);
        const float* a2 = GADDR(tid + 512,  gy2);
        const float* a3 = GADDR(tid + 768,  gy3);
        float4 v0 = *(const float4*)a0;
        float4 v1 = *(const float4*)a1;
        float4 v2 = *(const float4*)a2;
        float4 v3 = *(const float4*)a3;
        float4 v4 = make_float4(0.f, 0.f, 0.f, 0.f);
        if (tid < 64) { const float* a4 = GADDR(tid + 1024, gy4); v4 = *(const float4*)a4; }
        #undef GADDR
        #define PIN(v) asm volatile("" : "+v"(v.x), "+v"(v.y), "+v"(v.z), "+v"(v.w))
        PIN(v0); PIN(v1); PIN(v2); PIN(v3); PIN(v4);
        #undef PIN

        __syncthreads();   // previous iteration's stencil reads complete

        #define STORE(K, V, GY) { \
            float4 vv = (V); \
            if ((GY) < 0 || (GY) > HH - 1) vv = make_float4(NEG, NEG, NEG, NEG); \
            *(float4*)&lds[(((K) >> 5) * WW) + (((K) & 31) << 2)] = vv; }
        STORE(tid,        v0, gy0)
        STORE(tid + 256,  v1, gy1)
        STORE(tid + 512,  v2, gy2)
        STORE(tid + 768,  v3, gy3)
        if (tid < 64) STORE(tid + 1024, v4, gy4)
        #undef STORE
        __syncthreads();

        // stencil: thread owns 4x4 px; rolling 3-row window from LDS
        int rg = tid >> 5;                    // row-group 0..7 (4 rows each)
        int tile_x = (tid & 31) << 2;
        int lrow = 1 + rg * 4;
        float4 A = *(const float4*)&lds[(lrow - 1) * WW + tile_x];
        float4 B = *(const float4*)&lds[lrow * WW + tile_x];
        int ccbase = bc * 32;
        uint64_t* cd = cand + (size_t)bc * CAP;
        int ibase = chan * HW + (ybase + rg * 4) * WW + tile_x;

        #pragma unroll
        for (int j = 0; j < 4; ++j) {
            float4 C = *(const float4*)&lds[(lrow + j + 1) * WW + tile_x];
            float c0 = fmaxf(fmaxf(A.x, B.x), C.x);
            float c1 = fmaxf(fmaxf(A.y, B.y), C.y);
            float c2 = fmaxf(fmaxf(A.z, B.z), C.z);
            float c3 = fmaxf(fmaxf(A.w, B.w), C.w);
            float cl = __shfl_up(c3, 1);      // cross-row pulls masked by tile_x tests
            float cr = __shfl_down(c0, 1);
            if (tile_x == 0)      cl = NEG;
            if (tile_x == WW - 4) cr = NEG;
            float w0 = fmaxf(fmaxf(cl, c0), c1);
            float w1 = fmaxf(fmaxf(c0, c1), c2);
            float w2 = fmaxf(fmaxf(c1, c2), c3);
            float w3 = fmaxf(fmaxf(c2, c3), cr);

            #define EMIT(Wm, V, P) \
                if ((Wm) == (V) && (V) >= VTHR) { \
                    uint32_t bt = __float_as_uint(sigmoidf(V)); \
                    int pos = atomicAdd(&ccnt[ccbase], 1); \
                    if (pos < CAP) \
                        cd[pos] = ((uint64_t)bt << 32) | \
                                  (uint32_t)(~(uint32_t)(ibase + j * WW + (P))); \
                }
            EMIT(w0, B.x, 0)
            EMIT(w1, B.y, 1)
            EMIT(w2, B.z, 2)
            EMIT(w3, B.w, 3)
            #undef EMIT
            A = B; B = C;
        }
    }
}

// on-the-fly key for the fallback (never expected on this input)
__device__ uint64_t key_at(const float* __restrict__ hb, int i) {
    float v = hb[i];
    int rem = i & (HW - 1);
    int y = rem >> 7, x = rem & (WW - 1);
    bool mx = true;
    if (y > 0) {
        if (x > 0      && hb[i - WW - 1] > v) mx = false;
        if (              hb[i - WW    ] > v) mx = false;
        if (x < WW - 1 && hb[i - WW + 1] > v) mx = false;
    }
    if (x > 0      && hb[i - 1] > v) mx = false;
    if (x < WW - 1 && hb[i + 1] > v) mx = false;
    if (y < HH - 1) {
        if (x > 0      && hb[i + WW - 1] > v) mx = false;
        if (              hb[i + WW    ] > v) mx = false;
        if (x < WW - 1 && hb[i + WW + 1] > v) mx = false;
    }
    if (!mx) return 0;
    return ((uint64_t)__float_as_uint(sigmoidf(v)) << 32) | (uint32_t)(~(uint32_t)i);
}

// descending bitonic sort of N u64 keys in LDS
template <int N>
__device__ void bitonic_desc(uint64_t* k) {
    for (int kk = 2; kk <= N; kk <<= 1) {
        for (int j = kk >> 1; j > 0; j >>= 1) {
            __syncthreads();
            for (int i = threadIdx.x; i < N; i += blockDim.x) {
                int l = i ^ j;
                if (l > i) {
                    uint64_t a = k[i], b = k[l];
                    bool up = ((i & kk) == 0);
                    if (up ? (a < b) : (a > b)) { k[i] = b; k[l] = a; }
                }
            }
        }
    }
    __syncthreads();
}

// ---- kernel 2: select top-100 per (tensor,batch), with FUSED exact fallback ----
__global__ void __launch_bounds__(1024) k_selectfb(
        const uint64_t* __restrict__ cand, const int* __restrict__ ccnt,
        const float* __restrict__ tl, const float* __restrict__ br,
        const float* __restrict__ ct,
        const float* __restrict__ tl_tag, const float* __restrict__ br_tag,
        const float* __restrict__ tl_regr, const float* __restrict__ br_regr,
        const float* __restrict__ ct_regr,
        float* __restrict__ cs, float* __restrict__ cx, float* __restrict__ cy,
        float* __restrict__ ce, int* __restrict__ ccls) {
    __shared__ uint64_t keys[CAP];       // 32 KB
    __shared__ uint32_t lh[NBINS];       // 16 KB (fallback only)
    __shared__ uint32_t csum[1024];      // 4 KB  (fallback only)
    __shared__ int thr_s, cnt_s;
    int tid = threadIdx.x;
    int bc = blockIdx.x; int t = bc >> 3; int b = bc & 7;
    int nf = ccnt[bc * 32];
    bool ok = (nf >= KTOP) && (nf <= CAP);
    int n;
    if (ok) {
        n = nf;
        int lim = (n <= 512) ? 512 : (n <= 2048) ? 2048 : CAP;
        for (int i = tid; i < lim; i += 1024)
            keys[i] = (i < n) ? cand[(size_t)bc * CAP + i] : 0ull;
    } else {
        // ---- exact fallback, fully in-block ----
        const float* heat = (t == 0) ? tl : (t == 1) ? br : ct;
        const float* hb = heat + (size_t)b * CHW;
        for (int i = tid; i < NBINS; i += 1024) lh[i] = 0;
        if (tid == 0) cnt_s = 0;
        __syncthreads();
        for (int i = tid; i < CHW; i += 1024) {
            uint64_t k = key_at(hb, i);
            if (k) atomicAdd(&lh[(uint32_t)(k >> 51)], 1u);
        }
        __syncthreads();
        uint32_t bins[4];
        #pragma unroll
        for (int i = 0; i < 4; ++i) bins[i] = lh[tid * 4 + i];
        if (tid == 0) bins[0] = 0;
        uint32_t s = bins[0] + bins[1] + bins[2] + bins[3];
        csum[tid] = s;
        __syncthreads();
        for (int step = 1; step < 1024; step <<= 1) {
            uint32_t add = (tid + step < 1024) ? csum[tid + step] : 0;
            __syncthreads();
            csum[tid] += add;
            __syncthreads();
        }
        uint32_t inc = csum[tid];
        uint32_t above = (tid < 1023) ? csum[tid + 1] : 0;
        if (tid == 0 && (int)inc < KTOP) thr_s = 1;
        if ((int)above < KTOP && (int)inc >= KTOP) {
            uint32_t cum = above;
            int T = 1;
            #pragma unroll
            for (int i = 3; i >= 0; --i) {
                cum += bins[i];
                if ((int)cum >= KTOP) { T = tid * 4 + i; break; }
            }
            thr_s = T;
        }
        __syncthreads();
        int T = thr_s;
        for (int i = tid; i < CHW; i += 1024) {
            uint64_t k = key_at(hb, i);
            if (k && (int)(uint32_t)(k >> 51) >= T) {
                int pc = atomicAdd(&cnt_s, 1);
                if (pc < CAP) keys[pc] = k;
            }
        }
        __syncthreads();
        n = cnt_s; if (n > CAP) n = CAP;
        int lim = (n <= 512) ? 512 : (n <= 2048) ? 2048 : CAP;
        for (int i = tid; i < lim; i += 1024) if (i >= n) keys[i] = 0;
    }
    if (n <= 512)       bitonic_desc<512>(keys);
    else if (n <= 2048) bitonic_desc<2048>(keys);
    else                bitonic_desc<CAP>(keys);

    if (tid < KTOP) {
        uint64_t key = keys[tid];
        float s2 = __uint_as_float((uint32_t)(key >> 32));
        uint32_t idx = ~(uint32_t)key;
        int cls = (int)(idx >> 14);
        int rem = (int)(idx & (HW - 1));
        int y = rem >> 7, x = rem & (WW - 1);
        const float* regr = (t == 0) ? tl_regr : (t == 1) ? br_regr : ct_regr;
        float o0 = regr[((size_t)b * 2 + 0) * HW + rem];
        float o1 = regr[((size_t)b * 2 + 1) * HW + rem];
        float emb = 0.f;
        if (t == 0) emb = tl_tag[(size_t)b * HW + rem];
        else if (t == 1) emb = br_tag[(size_t)b * HW + rem];
        int o = bc * KTOP + tid;
        cs[o] = s2;
        cx[o] = (float)x + o0;
        cy[o] = (float)y + o1;
        ce[o] = emb;
        ccls[o] = cls;
    }
}

// ---- kernel 3: fused pairwise scoring + final top-1000 + centers ----
__global__ void __launch_bounds__(1024) k_pairfinal(
        const float* __restrict__ cs, const float* __restrict__ cx,
        const float* __restrict__ cy, const float* __restrict__ ce,
        const int* __restrict__ ccls, float* __restrict__ out) {
    int b = blockIdx.x;
    __shared__ float ts[KTOP], tx[KTOP], ty[KTOP], te[KTOP];
    __shared__ int   tc[KTOP];
    __shared__ float bs_[KTOP], bx[KTOP], by[KTOP], be[KTOP];
    __shared__ int   bcl[KTOP];
    __shared__ uint64_t acc[ACAP];
    __shared__ int aidx[ACAP];
    __shared__ int acnt_s;
    int tid = threadIdx.x;
    if (tid == 0) acnt_s = 0;
    if (tid < KTOP) {
        int o = (0 * NB + b) * KTOP + tid;
        ts[tid] = cs[o]; tx[tid] = cx[o]; ty[tid] = cy[o]; te[tid] = ce[o]; tc[tid] = ccls[o];
    } else if (tid >= 512 && tid < 512 + KTOP) {
        int k = tid - 512;
        int o = (1 * NB + b) * KTOP + k;
        bs_[k] = cs[o]; bx[k] = cx[o]; by[k] = cy[o]; be[k] = ce[o]; bcl[k] = ccls[o];
    }
    __syncthreads();
    for (int p = tid; p < NPAIR; p += 1024) {
        int i = p / KTOP, j = p - i * KTOP;
        bool rej = (tc[i] != bcl[j])
                 | (fabsf(te[i] - be[j]) > 0.5f)
                 | (bx[j] < tx[i])
                 | (by[j] < ty[i]);
        if (!rej) {
            float sc = (ts[i] + bs_[j]) * 0.5f;
            int pos = atomicAdd(&acnt_s, 1);
            if (pos < ACAP)
                acc[pos] = ((uint64_t)__float_as_uint(sc) << 32) | (uint32_t)(~(uint32_t)p);
        }
    }
    __syncthreads();
    int m = acnt_s; if (m > ACAP) m = ACAP;
    if (m <= 256) {
        for (int i = tid; i < 256; i += 1024) if (i >= m) acc[i] = 0;
        bitonic_desc<256>(acc);
    } else {
        for (int i = tid; i < ACAP; i += 1024) if (i >= m) acc[i] = 0;
        bitonic_desc<ACAP>(acc);
    }
    for (int i = tid; i < m; i += 1024) aidx[i] = (int)(~(uint32_t)acc[i]);
    __syncthreads();
    for (int d = tid; d < NDET; d += 1024) {
        int p; float sc;
        if (d < m) {
            p = aidx[d];
            sc = __uint_as_float((uint32_t)(acc[d] >> 32));
        } else {
            // (d-m)-th flat pair-index NOT in accepted set, ascending (stable -1 ties)
            int r = d - m;
            int idx = r;
            for (;;) {
                int c = 0;
                for (int a = 0; a < m; ++a) c += (aidx[a] <= idx) ? 1 : 0;
                int ni = r + c;
                if (ni == idx) break;
                idx = ni;
            }
            p = idx; sc = -1.f;
        }
        int i = p / KTOP, j = p - i * KTOP;
        int ot = (0 * NB + b) * KTOP + i;
        int ob = (1 * NB + b) * KTOP + j;
        float* dr = out + ((size_t)b * NDET + d) * 8;
        dr[0] = cx[ot]; dr[1] = cy[ot]; dr[2] = cx[ob]; dr[3] = cy[ob];
        dr[4] = sc; dr[5] = cs[ot]; dr[6] = cs[ob]; dr[7] = (float)ccls[ot];
    }
    if (tid < KTOP) {
        int oc = (2 * NB + b) * KTOP + tid;
        float* cr = out + (size_t)NB * NDET * 8 + ((size_t)b * KTOP + tid) * 4;
        cr[0] = cx[oc]; cr[1] = cy[oc]; cr[2] = (float)ccls[oc]; cr[3] = cs[oc];
    }
}

extern "C" void kernel_launch(void* const* d_in, const int* in_sizes, int n_in,
                              void* d_out, int out_size, void* d_ws, size_t ws_size,
                              hipStream_t stream) {
    const float* tl_heat = (const float*)d_in[0];
    const float* br_heat = (const float*)d_in[1];
    const float* ct_heat = (const float*)d_in[2];
    const float* tl_tag  = (const float*)d_in[3];
    const float* br_tag  = (const float*)d_in[4];
    const float* tl_regr = (const float*)d_in[5];
    const float* br_regr = (const float*)d_in[6];
    const float* ct_regr = (const float*)d_in[7];

    if (ws_size < (size_t)WS_NEEDED) return;   // ~0.84 MB

    char* ws = (char*)d_ws;
    int*      ccnt = (int*)(ws + OFF_CCNT);
    uint64_t* cand = (uint64_t*)(ws + OFF_CAND);
    float*    cs   = (float*)(ws + OFF_CS);
    float*    cx   = (float*)(ws + OFF_CX);
    float*    cy   = (float*)(ws + OFF_CY);
    float*    ce   = (float*)(ws + OFF_CE);
    int*      ccls = (int*)(ws + OFF_CCLS);

    hipMemsetAsync(ws, 0, ZERO_BYTES, stream);   // ccnt (3 KB)

    k_nms<<<NBLK, 256, 0, stream>>>(tl_heat, br_heat, ct_heat, cand, ccnt);
    k_selectfb<<<24, 1024, 0, stream>>>(cand, ccnt,
                                        tl_heat, br_heat, ct_heat,
                                        tl_tag, br_tag,
                                        tl_regr, br_regr, ct_regr,
                                        cs, cx, cy, ce, ccls);
    k_pairfinal<<<NB, 1024, 0, stream>>>(cs, cx, cy, ce, ccls, (float*)d_out);
}